// Round 2
// baseline (827.933 us; speedup 1.0000x reference)
//
#include <hip/hip_runtime.h>
#include <math.h>

typedef __attribute__((ext_vector_type(4))) float f32x4;
typedef __attribute__((ext_vector_type(8))) short s16x8;

constexpr int B = 32, T = 48, H = 256, E = 128, TD = 48;
constexpr int OUT = 40000, NOUTC = 40048, NPADC = 40064;
constexpr int G3 = 768, DIN = 176;

__device__ __forceinline__ float sigmoidf_(float x){ return 1.f/(1.f+__expf(-x)); }
__device__ __forceinline__ float tanhf_(float x){
  float e = __expf(2.f*x);            // inf-safe: x>>0 -> 1, x<<0 -> -1
  return 1.f - 2.f/(e + 1.f);
}
__device__ __forceinline__ unsigned short f2bf(float f){
  unsigned int u = __float_as_uint(f);
  u += 0x7fffu + ((u>>16)&1u);   // RNE
  return (unsigned short)(u>>16);
}
__device__ __forceinline__ s16x8 pack8(float4 u, float4 v){
  s16x8 r;
  r[0]=(short)f2bf(u.x); r[1]=(short)f2bf(u.y); r[2]=(short)f2bf(u.z); r[3]=(short)f2bf(u.w);
  r[4]=(short)f2bf(v.x); r[5]=(short)f2bf(v.y); r[6]=(short)f2bf(v.z); r[7]=(short)f2bf(v.w);
  return r;
}
__device__ __forceinline__ void gl_lds16(const unsigned short* g, unsigned short* l){
  __builtin_amdgcn_global_load_lds((const __attribute__((address_space(1))) void*)g,
                                   (__attribute__((address_space(3))) void*)l, 16, 0, 0);
}
// coherent-point (bypass per-XCD L2) 8B atomic ops: tag rides WITH payload, so a
// load returning the right tag is guaranteed to carry the right payload.
__device__ __forceinline__ void st_sc64(unsigned long long* p, unsigned long long v){
  __hip_atomic_store(p, v, __ATOMIC_RELAXED, __HIP_MEMORY_SCOPE_SYSTEM);
}
__device__ __forceinline__ unsigned long long ld_sc64(const unsigned long long* p){
  return __hip_atomic_load((unsigned long long*)p, __ATOMIC_RELAXED, __HIP_MEMORY_SCOPE_SYSTEM);
}

// ------- transpose w_ih0[:, :128] -> wT[e][g]; also zero the 16K exchange tags ------
__global__ void wt_kernel(const float* __restrict__ w_ih0, float* __restrict__ wT,
                          unsigned long long* __restrict__ exch64){
  int i = blockIdx.x*256 + threadIdx.x;       // over 128*768 = 98304 threads
  if (i < 16384) st_sc64(&exch64[i], 0ull);   // tag 0 matches no phase (1..48)
  if (i >= E*G3) return;
  int e = i / G3, g = i % G3;
  wT[i] = w_ih0[g*DIN + e];
}

// ---------------- K1: xp0[t*B+b][g] = emb(loc)·w_ih0[g,:128] + w_ih0[g,128+time] + b_ih0[g]
__global__ void xp0_kernel(const int* __restrict__ locations, const int* __restrict__ times,
                           const float* __restrict__ embed, const float* __restrict__ wT,
                           const float* __restrict__ w_ih0, const float* __restrict__ b_ih0,
                           float* __restrict__ xp0)
{
  __shared__ float emb_s[16][E];
  __shared__ int tm_s[16];
  const int r0 = blockIdx.x * 16;
  const int tid = threadIdx.x;
  for (int i = tid; i < 16*E; i += 256) {
    int p = i >> 7, e = i & 127;
    int r = r0 + p; int t = r >> 5, b = r & 31;
    emb_s[p][e] = embed[(size_t)locations[b*T + t]*E + e];
  }
  if (tid < 16) {
    int r = r0 + tid; int t = r >> 5, b = r & 31;
    tm_s[tid] = times[b*T + t];
  }
  __syncthreads();
  const int g = tid;  // gate rows g, g+256, g+512
  float acc[16][3];
  #pragma unroll
  for (int p=0;p<16;p++){acc[p][0]=0.f;acc[p][1]=0.f;acc[p][2]=0.f;}
  for (int e = 0; e < E; e += 4) {
    float w0_[4], w1_[4], w2_[4];
    #pragma unroll
    for (int i=0;i<4;i++){
      w0_[i]=wT[(e+i)*G3 + g];
      w1_[i]=wT[(e+i)*G3 + 256 + g];
      w2_[i]=wT[(e+i)*G3 + 512 + g];
    }
    #pragma unroll
    for (int p=0;p<16;p++){
      float4 ev = *(const float4*)&emb_s[p][e];
      acc[p][0] += ev.x*w0_[0]+ev.y*w0_[1]+ev.z*w0_[2]+ev.w*w0_[3];
      acc[p][1] += ev.x*w1_[0]+ev.y*w1_[1]+ev.z*w1_[2]+ev.w*w1_[3];
      acc[p][2] += ev.x*w2_[0]+ev.y*w2_[1]+ev.z*w2_[2]+ev.w*w2_[3];
    }
  }
  #pragma unroll
  for (int p=0;p<16;p++){
    int r = r0+p; int tt = tm_s[p];
    xp0[(size_t)r*G3 + g]       = acc[p][0] + b_ih0[g]     + w_ih0[g*DIN       + E + tt];
    xp0[(size_t)r*G3 + 256 + g] = acc[p][1] + b_ih0[g+256] + w_ih0[(g+256)*DIN + E + tt];
    xp0[(size_t)r*G3 + 512 + g] = acc[p][2] + b_ih0[g+512] + w_ih0[(g+512)*DIN + E + tt];
  }
}

// ---------------- K2: cooperative 2-layer GRU, MFMA recurrence, weights in VGPRs -----
// 16 blocks x 384 threads (6 waves = 2 m-tiles x 3 gates). L0 step t=p, L1 step t=p-1.
// Cross-block h exchange: per-word {payload|tag} 8B system-scope atomics + speculative
// burst-load with per-word retry. NO barrier, NO flag, NO vmcnt drain: one MALL round
// trip per step instead of three. 2-deep parity slots; tag-gating gives back-pressure.
struct GruArgs {
  const float* xp0; const float* traj; const int* labels;
  const float* w_hh0; const float* b_hh0;
  const float* w_ih1; const float* w_hh1; const float* b_ih1; const float* b_hh1;
  unsigned long long* exch;  // [parity 2][state 2][b 32][colpair 128] : {2xbf16 | tag}
  unsigned short* abf;       // [(b*48+t)*256 + j] relu-bf16 FC input
};

__global__ void __launch_bounds__(384, 1) gru_kernel(GruArgs a)
{
  __shared__ unsigned short Ash[2][32*264]; // [0]=h0/y0, [1]=h1 bf16, row stride 264
  __shared__ float gl0[3*32*17];            // L0 gate pre-acts (hr,hz,hn)
  __shared__ float gl1[4*32*17];            // L1 gate pre-acts (r,z,nx,nh)
  __shared__ float hF0[512];                // private fp32 carry, [b*16 + jlocal]
  __shared__ float hF1[512];
  const int tid  = threadIdx.x;
  const int jt   = blockIdx.x;            // j-tile [jt*16, jt*16+16)
  const int wv   = tid >> 6;              // 0..5
  const int lane = tid & 63;
  const int g    = wv % 3, mt = wv / 3;   // gate, m-tile
  const int fn   = lane & 15;             // fragment n (out row) / m (batch)
  const int fq   = lane >> 4;             // quad -> k offset fq*8

  // ---- B fragments (weights) loaded ONCE into registers ----
  const int row = g*256 + jt*16 + fn;
  s16x8 b0[8], b1[16];
  #pragma unroll
  for (int kk = 0; kk < 8; ++kk) {
    const float* p0 = a.w_hh0 + (size_t)row*H + kk*32 + fq*8;
    const float* p1 = a.w_ih1 + (size_t)row*H + kk*32 + fq*8;
    const float* p2 = a.w_hh1 + (size_t)row*H + kk*32 + fq*8;
    b0[kk]    = pack8(*(const float4*)p0, *(const float4*)(p0+4));
    b1[kk]    = pack8(*(const float4*)p1, *(const float4*)(p1+4));
    b1[kk+8]  = pack8(*(const float4*)p2, *(const float4*)(p2+4));
  }

  // ---- init hidden from traj table (torch reshape(2,32,256) view), built LOCALLY ----
  for (int i = tid; i < 2*B*H; i += 384) {
    int l = i >> 13, bb = (i >> 8) & 31, h = i & 255;
    float v = a.traj[(size_t)a.labels[l*16 + (bb>>1)]*512 + (bb&1)*256 + h];
    Ash[l][bb*264 + h] = f2bf(v);
  }
  if (tid < 256) {    // own-column fp32 carries + publish h1-init (slot 1, tag 1)
    int b = tid >> 3, jp = tid & 7, j0 = jp*2, gj = jt*16 + j0;
    float v00 = a.traj[(size_t)a.labels[(b>>1)]*512      + (b&1)*256 + gj];
    float v01 = a.traj[(size_t)a.labels[(b>>1)]*512      + (b&1)*256 + gj+1];
    float v10 = a.traj[(size_t)a.labels[16 + (b>>1)]*512 + (b&1)*256 + gj];
    float v11 = a.traj[(size_t)a.labels[16 + (b>>1)]*512 + (b&1)*256 + gj+1];
    hF0[b*16+j0] = v00; hF0[b*16+j0+1] = v01;
    hF1[b*16+j0] = v10; hF1[b*16+j0+1] = v11;
    unsigned pay = (unsigned)f2bf(v10) | ((unsigned)f2bf(v11) << 16);
    st_sc64(&a.exch[(size_t)(1*2 + 1)*4096 + b*128 + jt*8 + jp],
            (unsigned long long)pay | (1ull << 32));
  }

  for (int p = 0; p <= T; ++p) {
    const int cur = p & 1, nxt = cur ^ 1;
    // ---- stage exchanged h0/y0 and h1 into LDS: burst-load + per-word tag retry ----
    if (p) {
      const unsigned long long* src = a.exch + (size_t)cur*8192;
      const unsigned want = (unsigned)p;
      unsigned long long v[22];
      #pragma unroll
      for (int k = 0; k < 22; ++k) {
        int i = tid + k*384;
        if (i < 8192) v[k] = ld_sc64(&src[i]);
      }
      unsigned pend = 0;
      #pragma unroll
      for (int k = 0; k < 22; ++k) {
        int i = tid + k*384;
        if (i < 8192 && (unsigned)(v[k] >> 32) != want) pend |= (1u << k);
      }
      int guard = 0;
      while (pend && ++guard < (1 << 20)) {   // bounded: never hard-hang the queue
        #pragma unroll
        for (int k = 0; k < 22; ++k)
          if (pend & (1u << k)) v[k] = ld_sc64(&src[tid + k*384]);
        #pragma unroll
        for (int k = 0; k < 22; ++k)
          if ((pend & (1u << k)) && (unsigned)(v[k] >> 32) == want) pend &= ~(1u << k);
      }
      #pragma unroll
      for (int k = 0; k < 22; ++k) {
        int i = tid + k*384;
        if (i < 8192) {
          int st = i >> 12, bb = (i >> 7) & 31, cp = i & 127;
          *(unsigned*)&Ash[st][bb*264 + cp*2] = (unsigned)v[k];
        }
      }
    }
    __syncthreads();

    // ---- MFMA phase ----
    if (p < T) {            // L0, t = p: gates_h = h0 @ w_hh0^T
      f32x4 acc = (f32x4){0.f,0.f,0.f,0.f};
      #pragma unroll
      for (int kk = 0; kk < 8; ++kk) {
        s16x8 af = *(const s16x8*)&Ash[0][(mt*16 + fn)*264 + kk*32 + fq*8];
        acc = __builtin_amdgcn_mfma_f32_16x16x32_bf16(af, b0[kk], acc, 0, 0, 0);
      }
      #pragma unroll
      for (int i = 0; i < 4; ++i)
        gl0[(g*32 + mt*16 + fq*4 + i)*17 + fn] = acc[i];
    }
    if (p >= 1) {           // L1, t = p-1: x = y0 (Ash[0]), h = h1 (Ash[1])
      if (g < 2) {          // r,z: concat-K is valid
        f32x4 acc = (f32x4){0.f,0.f,0.f,0.f};
        #pragma unroll
        for (int kk = 0; kk < 8; ++kk) {
          s16x8 af = *(const s16x8*)&Ash[0][(mt*16 + fn)*264 + kk*32 + fq*8];
          acc = __builtin_amdgcn_mfma_f32_16x16x32_bf16(af, b1[kk], acc, 0, 0, 0);
        }
        #pragma unroll
        for (int kk = 0; kk < 8; ++kk) {
          s16x8 af = *(const s16x8*)&Ash[1][(mt*16 + fn)*264 + kk*32 + fq*8];
          acc = __builtin_amdgcn_mfma_f32_16x16x32_bf16(af, b1[8+kk], acc, 0, 0, 0);
        }
        #pragma unroll
        for (int i = 0; i < 4; ++i)
          gl1[(g*32 + mt*16 + fq*4 + i)*17 + fn] = acc[i];
      } else {              // n: x-part and h-part must stay separate (r * h-part)
        f32x4 ax = (f32x4){0.f,0.f,0.f,0.f}, ah = (f32x4){0.f,0.f,0.f,0.f};
        #pragma unroll
        for (int kk = 0; kk < 8; ++kk) {
          s16x8 afx = *(const s16x8*)&Ash[0][(mt*16 + fn)*264 + kk*32 + fq*8];
          s16x8 afh = *(const s16x8*)&Ash[1][(mt*16 + fn)*264 + kk*32 + fq*8];
          ax = __builtin_amdgcn_mfma_f32_16x16x32_bf16(afx, b1[kk],   ax, 0, 0, 0);
          ah = __builtin_amdgcn_mfma_f32_16x16x32_bf16(afh, b1[8+kk], ah, 0, 0, 0);
        }
        #pragma unroll
        for (int i = 0; i < 4; ++i) {
          gl1[(2*32 + mt*16 + fq*4 + i)*17 + fn] = ax[i];
          gl1[(3*32 + mt*16 + fq*4 + i)*17 + fn] = ah[i];
        }
      }
    }
    __syncthreads();

    // ---- pointwise update (fp32 carry in LDS, publish {payload|tag p+1} words) ----
    if (tid < 256) {
      const int b = tid >> 3, jp = tid & 7, j0 = jp*2, gj = jt*16 + j0;
      const unsigned long long tagw = ((unsigned long long)(unsigned)(p + 1)) << 32;
      if (p < T) {          // L0, t = p
        const float* xp = a.xp0 + (size_t)(p*B + b)*G3 + gj;
        float r0 = sigmoidf_(xp[0]   + gl0[(b)*17+j0]      + a.b_hh0[gj]);
        float r1 = sigmoidf_(xp[1]   + gl0[(b)*17+j0+1]    + a.b_hh0[gj+1]);
        float z0 = sigmoidf_(xp[256] + gl0[(32+b)*17+j0]   + a.b_hh0[256+gj]);
        float z1 = sigmoidf_(xp[257] + gl0[(32+b)*17+j0+1] + a.b_hh0[256+gj+1]);
        float n0 = tanhf_(xp[512] + r0*(gl0[(64+b)*17+j0]   + a.b_hh0[512+gj]));
        float n1 = tanhf_(xp[513] + r1*(gl0[(64+b)*17+j0+1] + a.b_hh0[512+gj+1]));
        float h0n = (1.f - z0)*n0 + z0*hF0[b*16+j0];
        float h1n = (1.f - z1)*n1 + z1*hF0[b*16+j0+1];
        hF0[b*16+j0] = h0n; hF0[b*16+j0+1] = h1n;
        unsigned pay = (unsigned)f2bf(h0n) | ((unsigned)f2bf(h1n) << 16);
        st_sc64(&a.exch[(size_t)(nxt*2 + 0)*4096 + b*128 + jt*8 + jp],
                (unsigned long long)pay | tagw);
      }
      if (p >= 1) {         // L1, t = p - 1
        const int t1 = p - 1;
        float r0 = sigmoidf_(gl1[(b)*17+j0]      + a.b_ih1[gj]     + a.b_hh1[gj]);
        float r1 = sigmoidf_(gl1[(b)*17+j0+1]    + a.b_ih1[gj+1]   + a.b_hh1[gj+1]);
        float z0 = sigmoidf_(gl1[(32+b)*17+j0]   + a.b_ih1[256+gj]   + a.b_hh1[256+gj]);
        float z1 = sigmoidf_(gl1[(32+b)*17+j0+1] + a.b_ih1[256+gj+1] + a.b_hh1[256+gj+1]);
        float n0 = tanhf_(gl1[(64+b)*17+j0]   + a.b_ih1[512+gj]
                          + r0*(gl1[(96+b)*17+j0]   + a.b_hh1[512+gj]));
        float n1 = tanhf_(gl1[(64+b)*17+j0+1] + a.b_ih1[512+gj+1]
                          + r1*(gl1[(96+b)*17+j0+1] + a.b_hh1[512+gj+1]));
        float h0n = (1.f - z0)*n0 + z0*hF1[b*16+j0];
        float h1n = (1.f - z1)*n1 + z1*hF1[b*16+j0+1];
        hF1[b*16+j0] = h0n; hF1[b*16+j0+1] = h1n;
        unsigned pay = (unsigned)f2bf(h0n) | ((unsigned)f2bf(h1n) << 16);
        st_sc64(&a.exch[(size_t)(nxt*2 + 1)*4096 + b*128 + jt*8 + jp],
                (unsigned long long)pay | tagw);
        ((unsigned*)a.abf)[((size_t)(b*T + t1)*H + gj) >> 1] =
              (unsigned)f2bf(fmaxf(h0n,0.f)) | ((unsigned)f2bf(fmaxf(h1n,0.f)) << 16);
      }
    }
    // no barrier: next phase's tag-gated loads provide all needed ordering
  }
}

// ---------------- cast fc_w to bf16 (pad cols to 40064 with zero rows) ---------------
__global__ void castw_kernel(const float* __restrict__ fcw, unsigned short* __restrict__ wbf){
  int g = blockIdx.x*256 + threadIdx.x;   // float4 groups, NPADC*64 total
  if (g >= NPADC*64) return;
  int row = g >> 6;
  ushort4 o;
  if (row < NOUTC) {
    float4 v = ((const float4*)fcw)[g];
    o.x=f2bf(v.x); o.y=f2bf(v.y); o.z=f2bf(v.z); o.w=f2bf(v.w);
  } else { o.x=0; o.y=0; o.z=0; o.w=0; }
  ((ushort4*)wbf)[g] = o;
}

// ---------------- K4: bf16 MFMA GEMM  C[1536 x 40048] = A·W^T + b -> raw logits ------
__global__ void __launch_bounds__(256) gemm_kernel(const unsigned short* __restrict__ Abf,
                                                   const unsigned short* __restrict__ Wbf,
                                                   const float* __restrict__ fc_b,
                                                   float* __restrict__ dout)
{
  __shared__ unsigned short As[128*32];
  __shared__ unsigned short Ws[128*32];
  const int m0 = blockIdx.x * 128;
  const int n0 = blockIdx.y * 128;
  const int tid = threadIdx.x;
  const int lane = tid & 63;
  const int wv = tid >> 6;
  f32x4 acc[2][8];
  #pragma unroll
  for (int i=0;i<2;i++)
    #pragma unroll
    for(int jx=0;jx<8;jx++) acc[i][jx] = (f32x4){0.f,0.f,0.f,0.f};

  const int srow = tid >> 2;
  const int skoff = (tid & 3) * 8;
  const unsigned short* aptr = Abf + (size_t)(m0 + srow)*256 + skoff;
  const unsigned short* wptr = Wbf + (size_t)(n0 + srow)*256 + skoff;
  unsigned short* asd = &As[tid*8];
  unsigned short* wsd = &Ws[tid*8];

  const int fr = lane & 15;
  const int fk = (lane >> 4) * 8;

  for (int kk = 0; kk < 256; kk += 32) {
    gl_lds16(aptr + kk,            asd);
    gl_lds16(aptr + 64*256 + kk,   asd + 64*32);
    gl_lds16(wptr + kk,            wsd);
    gl_lds16(wptr + 64*256 + kk,   wsd + 64*32);
    __syncthreads();
    s16x8 a0 = *(const s16x8*)&As[(wv*32 + fr)*32 + fk];
    s16x8 a1 = *(const s16x8*)&As[(wv*32 + 16 + fr)*32 + fk];
    #pragma unroll
    for (int ct = 0; ct < 8; ++ct) {
      s16x8 bfr = *(const s16x8*)&Ws[(ct*16 + fr)*32 + fk];
      acc[0][ct] = __builtin_amdgcn_mfma_f32_16x16x32_bf16(a0, bfr, acc[0][ct], 0, 0, 0);
      acc[1][ct] = __builtin_amdgcn_mfma_f32_16x16x32_bf16(a1, bfr, acc[1][ct], 0, 0, 0);
    }
    __syncthreads();
  }

  const int quad = lane >> 4;
  #pragma unroll
  for (int rt = 0; rt < 2; ++rt) {
    #pragma unroll
    for (int ct = 0; ct < 8; ++ct) {
      int col = n0 + ct*16 + fr;
      if (col < NOUTC) {
        float bias = fc_b[col];
        #pragma unroll
        for (int i = 0; i < 4; ++i) {
          int row = m0 + wv*32 + rt*16 + quad*4 + i;
          float v = acc[rt][ct][i] + bias;
          if (col < OUT) dout[(size_t)row*OUT + col] = v;
          else dout[(size_t)OUT*B*T + (size_t)row*TD + (col - OUT)] = v;
        }
      }
    }
  }
}

// ---------------- K5: per-row online logsumexp over the 40000 loc logits -------------
__global__ void stats_kernel(const float* __restrict__ dout, float* __restrict__ logz){
  const int r = blockIdx.x;
  const float4* row = (const float4*)(dout + (size_t)r*OUT);
  float m = -INFINITY, s = 0.f;
  for (int i = threadIdx.x; i < OUT/4; i += 256) {
    float4 v = row[i];
    float mx = fmaxf(fmaxf(v.x,v.y), fmaxf(v.z,v.w));
    if (mx > m) { s *= __expf(m - mx); m = mx; }
    s += __expf(v.x-m)+__expf(v.y-m)+__expf(v.z-m)+__expf(v.w-m);
  }
  #pragma unroll
  for (int off = 1; off < 64; off <<= 1) {
    float m2 = __shfl_xor(m, off);
    float s2 = __shfl_xor(s, off);
    float nm = fmaxf(m, m2);
    s = s*__expf(m-nm) + s2*__expf(m2-nm);
    m = nm;
  }
  __shared__ float sm[4], ss[4];
  if ((threadIdx.x & 63) == 0){ sm[threadIdx.x>>6]=m; ss[threadIdx.x>>6]=s; }
  __syncthreads();
  if (threadIdx.x == 0){
    float M=sm[0], S=ss[0];
    #pragma unroll
    for (int w=1;w<4;w++){
      float nm=fmaxf(M,sm[w]); S = S*__expf(M-nm)+ss[w]*__expf(sm[w]-nm); M=nm;
    }
    logz[r] = M + logf(S);
  }
}

// ---------------- K6: in-place normalize loc ----------------------------------------
__global__ void norm_kernel(float* __restrict__ dout, const float* __restrict__ logz){
  size_t i = (size_t)blockIdx.x*256 + threadIdx.x;   // float4 index
  if (i >= (size_t)B*T*OUT/4) return;
  int r = (int)(i / (OUT/4));
  float lz = logz[r];
  float4* p = (float4*)dout + i;
  float4 v = *p;
  v.x -= lz; v.y -= lz; v.z -= lz; v.w -= lz;
  *p = v;
}

// ---------------- K7: tm log_softmax (48 wide), in place -----------------------------
__global__ void tm_kernel(float* __restrict__ dout){
  const int r = blockIdx.x;
  const int lane = threadIdx.x;   // 64
  float* base = dout + (size_t)OUT*B*T + (size_t)r*TD;
  float v = (lane < TD) ? base[lane] : -INFINITY;
  float m = v;
  #pragma unroll
  for (int off=32; off; off>>=1) m = fmaxf(m, __shfl_xor(m, off));
  float e = (lane < TD) ? __expf(v - m) : 0.f;
  float s = e;
  #pragma unroll
  for (int off=32; off; off>>=1) s += __shfl_xor(s, off);
  float lz = m + logf(s);
  if (lane < TD) base[lane] = v - lz;
}

extern "C" void kernel_launch(void* const* d_in, const int* in_sizes, int n_in,
                              void* d_out, int out_size, void* d_ws, size_t ws_size,
                              hipStream_t stream)
{
  const int*   locations = (const int*)d_in[0];
  const int*   times     = (const int*)d_in[1];
  const int*   labels    = (const int*)d_in[2];
  const float* embed     = (const float*)d_in[3];
  const float* traj      = (const float*)d_in[4];
  const float* fc_w      = (const float*)d_in[5];
  const float* fc_b      = (const float*)d_in[6];
  const float* w_ih0     = (const float*)d_in[7];
  const float* w_hh0     = (const float*)d_in[8];
  const float* b_ih0     = (const float*)d_in[9];
  const float* b_hh0     = (const float*)d_in[10];
  const float* w_ih1     = (const float*)d_in[11];
  const float* w_hh1     = (const float*)d_in[12];
  const float* b_ih1     = (const float*)d_in[13];
  const float* b_hh1     = (const float*)d_in[14];
  float* out = (float*)d_out;
  char* ws = (char*)d_ws;

  float* xp0                 = (float*)(ws);                    // 4,718,592 B
  unsigned long long* exch   = (unsigned long long*)(ws + 4718592); // 131,072
  float* logz                = (float*)(ws + 4849664);          //     6,144
  unsigned short* abf        = (unsigned short*)(ws + 4855808); //   786,432
  unsigned short* wbf        = (unsigned short*)(ws + 5642240); // 20,512,768
  float* wT                  = (float*)(ws + 26155008);         //   393,216 -> ~26.5 MB

  castw_kernel<<<dim3((NPADC*64 + 255)/256), dim3(256), 0, stream>>>(fc_w, wbf);
  wt_kernel<<<dim3((E*G3 + 255)/256), dim3(256), 0, stream>>>(w_ih0, wT, exch);
  xp0_kernel<<<dim3(96), dim3(256), 0, stream>>>(locations, times, embed, wT, w_ih0, b_ih0, xp0);

  GruArgs ga{xp0, traj, labels, w_hh0, b_hh0, w_ih1, w_hh1, b_ih1, b_hh1,
             exch, abf};
  void* kargs[] = { &ga };
  hipLaunchCooperativeKernel((void*)gru_kernel, dim3(16), dim3(384), kargs, 0, stream);

  gemm_kernel<<<dim3(12, 313), dim3(256), 0, stream>>>(abf, wbf, fc_b, out);
  stats_kernel<<<dim3(B*T), dim3(256), 0, stream>>>(out, logz);
  norm_kernel<<<dim3((B*T*OUT/4 + 255)/256), dim3(256), 0, stream>>>(out, logz);
  tm_kernel<<<dim3(B*T), dim3(64), 0, stream>>>(out);
}

// Round 3
// 720.160 us; speedup vs baseline: 1.1497x; 1.1497x over previous
//
#include <hip/hip_runtime.h>
#include <math.h>

typedef __attribute__((ext_vector_type(4))) float f32x4;
typedef __attribute__((ext_vector_type(8))) short s16x8;

constexpr int B = 32, T = 48, H = 256, E = 128, TD = 48;
constexpr int OUT = 40000, NOUTC = 40048, NPADC = 40064;
constexpr int G3 = 768, DIN = 176;
constexpr int NT = 313, NTP = 320;   // gemm col-tiles (40064/128) for stats partials

__device__ __forceinline__ float sigmoidf_(float x){ return 1.f/(1.f+__expf(-x)); }
__device__ __forceinline__ float tanhf_(float x){
  float e = __expf(2.f*x);            // inf-safe: x>>0 -> 1, x<<0 -> -1
  return 1.f - 2.f/(e + 1.f);
}
__device__ __forceinline__ unsigned short f2bf(float f){
  unsigned int u = __float_as_uint(f);
  u += 0x7fffu + ((u>>16)&1u);   // RNE
  return (unsigned short)(u>>16);
}
__device__ __forceinline__ s16x8 pack8(float4 u, float4 v){
  s16x8 r;
  r[0]=(short)f2bf(u.x); r[1]=(short)f2bf(u.y); r[2]=(short)f2bf(u.z); r[3]=(short)f2bf(u.w);
  r[4]=(short)f2bf(v.x); r[5]=(short)f2bf(v.y); r[6]=(short)f2bf(v.z); r[7]=(short)f2bf(v.w);
  return r;
}
__device__ __forceinline__ void gl_lds16(const unsigned short* g, unsigned short* l){
  __builtin_amdgcn_global_load_lds((const __attribute__((address_space(1))) void*)g,
                                   (__attribute__((address_space(3))) void*)l, 16, 0, 0);
}
// system-scope (bypass per-XCD L2) relaxed ops; these lower to plain flagged
// vector loads/stores -> full wave coalescing, unlike RMW atomics.
__device__ __forceinline__ void st_sc(unsigned* p, unsigned v){
  __hip_atomic_store(p, v, __ATOMIC_RELAXED, __HIP_MEMORY_SCOPE_SYSTEM);
}
__device__ __forceinline__ unsigned ld_sc32(const unsigned* p){
  return __hip_atomic_load((unsigned*)p, __ATOMIC_RELAXED, __HIP_MEMORY_SCOPE_SYSTEM);
}
__device__ __forceinline__ unsigned long long ld_sc64(const unsigned long long* p){
  return __hip_atomic_load((unsigned long long*)p, __ATOMIC_RELAXED, __HIP_MEMORY_SCOPE_SYSTEM);
}

// ------- transpose w_ih0[:, :128] -> wT[e][g]; also zero the 32 flag words ----------
__global__ void wt_kernel(const float* __restrict__ w_ih0, float* __restrict__ wT,
                          unsigned* __restrict__ flags){
  int i = blockIdx.x*256 + threadIdx.x;       // over 128*768
  if (blockIdx.x == 0 && threadIdx.x < 32)
    __hip_atomic_store(&flags[threadIdx.x], 0u, __ATOMIC_RELAXED, __HIP_MEMORY_SCOPE_SYSTEM);
  if (i >= E*G3) return;
  int e = i / G3, g = i % G3;
  wT[i] = w_ih0[g*DIN + e];
}

// ---------------- K1: xp0[t*B+b][g] = emb(loc)·w_ih0[g,:128] + w_ih0[g,128+time] + b_ih0[g]
__global__ void xp0_kernel(const int* __restrict__ locations, const int* __restrict__ times,
                           const float* __restrict__ embed, const float* __restrict__ wT,
                           const float* __restrict__ w_ih0, const float* __restrict__ b_ih0,
                           float* __restrict__ xp0)
{
  __shared__ float emb_s[16][E];
  __shared__ int tm_s[16];
  const int r0 = blockIdx.x * 16;
  const int tid = threadIdx.x;
  for (int i = tid; i < 16*E; i += 256) {
    int p = i >> 7, e = i & 127;
    int r = r0 + p; int t = r >> 5, b = r & 31;
    emb_s[p][e] = embed[(size_t)locations[b*T + t]*E + e];
  }
  if (tid < 16) {
    int r = r0 + tid; int t = r >> 5, b = r & 31;
    tm_s[tid] = times[b*T + t];
  }
  __syncthreads();
  const int g = tid;  // gate rows g, g+256, g+512
  float acc[16][3];
  #pragma unroll
  for (int p=0;p<16;p++){acc[p][0]=0.f;acc[p][1]=0.f;acc[p][2]=0.f;}
  for (int e = 0; e < E; e += 4) {
    float w0_[4], w1_[4], w2_[4];
    #pragma unroll
    for (int i=0;i<4;i++){
      w0_[i]=wT[(e+i)*G3 + g];
      w1_[i]=wT[(e+i)*G3 + 256 + g];
      w2_[i]=wT[(e+i)*G3 + 512 + g];
    }
    #pragma unroll
    for (int p=0;p<16;p++){
      float4 ev = *(const float4*)&emb_s[p][e];
      acc[p][0] += ev.x*w0_[0]+ev.y*w0_[1]+ev.z*w0_[2]+ev.w*w0_[3];
      acc[p][1] += ev.x*w1_[0]+ev.y*w1_[1]+ev.z*w1_[2]+ev.w*w1_[3];
      acc[p][2] += ev.x*w2_[0]+ev.y*w2_[1]+ev.z*w2_[2]+ev.w*w2_[3];
    }
  }
  #pragma unroll
  for (int p=0;p<16;p++){
    int r = r0+p; int tt = tm_s[p];
    xp0[(size_t)r*G3 + g]       = acc[p][0] + b_ih0[g]     + w_ih0[g*DIN       + E + tt];
    xp0[(size_t)r*G3 + 256 + g] = acc[p][1] + b_ih0[g+256] + w_ih0[(g+256)*DIN + E + tt];
    xp0[(size_t)r*G3 + 512 + g] = acc[p][2] + b_ih0[g+512] + w_ih0[(g+512)*DIN + E + tt];
  }
}

// ---------------- K2: cooperative 2-layer GRU, MFMA recurrence, weights in VGPRs -----
// 16 blocks x 384 threads. Cross-block h exchange: bulk payload (pure 32KB/step) via
// coalesced system-scope loads issued ONCE, gated by a per-block flag in ONE 64B line
// (flag stored after per-wave vmcnt(0) drain + block barrier => payload guaranteed
// visible when flag observed). Polling traffic ~100B/block/round -> no fabric storm.
struct GruArgs {
  const float* xp0; const float* traj; const int* labels;
  const float* w_hh0; const float* b_hh0;
  const float* w_ih1; const float* w_hh1; const float* b_ih1; const float* b_hh1;
  unsigned* exch;     // [parity 2][jt 16][state 2][b 32][jp 8] u32 = {2x bf16}
  unsigned* flags;    // [parity 2][16] u32 step stamps (one 64B line per parity)
  unsigned short* abf;
};

__global__ void __launch_bounds__(384, 2) gru_kernel(GruArgs a)
{
  __shared__ unsigned short Ash[2][32*264]; // [0]=h0/y0, [1]=h1 bf16, row stride 264
  __shared__ float gl0[3*32*17];            // L0 gate pre-acts (hr,hz,hn)
  __shared__ float gl1[4*32*17];            // L1 gate pre-acts (r,z,nx,nh)
  const int tid  = threadIdx.x;
  const int jt   = blockIdx.x;
  const int wv   = tid >> 6;
  const int lane = tid & 63;
  const int g    = wv % 3, mt = wv / 3;
  const int fn   = lane & 15;
  const int fq   = lane >> 4;

  // ---- B fragments (weights) loaded ONCE into registers ----
  const int row = g*256 + jt*16 + fn;
  s16x8 b0[8], b1[16];
  #pragma unroll
  for (int kk = 0; kk < 8; ++kk) {
    const float* p0 = a.w_hh0 + (size_t)row*H + kk*32 + fq*8;
    const float* p1 = a.w_ih1 + (size_t)row*H + kk*32 + fq*8;
    const float* p2 = a.w_hh1 + (size_t)row*H + kk*32 + fq*8;
    b0[kk]    = pack8(*(const float4*)p0, *(const float4*)(p0+4));
    b1[kk]    = pack8(*(const float4*)p1, *(const float4*)(p1+4));
    b1[kk+8]  = pack8(*(const float4*)p2, *(const float4*)(p2+4));
  }

  // ---- pointwise thread identity, bias preload, fp32 carries in REGISTERS ----
  const int pb = tid >> 3, pjp = tid & 7, pj0 = pjp*2, pgj = jt*16 + pj0;
  float2 bh0r, bh0z, bh0n, bi1r, bi1z, bi1n, bh1r, bh1z, bh1n;
  float hc00 = 0.f, hc01 = 0.f, hc10 = 0.f, hc11 = 0.f;
  if (tid < 256) {
    bh0r = *(const float2*)&a.b_hh0[pgj];
    bh0z = *(const float2*)&a.b_hh0[256+pgj];
    bh0n = *(const float2*)&a.b_hh0[512+pgj];
    bi1r = *(const float2*)&a.b_ih1[pgj];
    bi1z = *(const float2*)&a.b_ih1[256+pgj];
    bi1n = *(const float2*)&a.b_ih1[512+pgj];
    bh1r = *(const float2*)&a.b_hh1[pgj];
    bh1z = *(const float2*)&a.b_hh1[256+pgj];
    bh1n = *(const float2*)&a.b_hh1[512+pgj];
  }

  // ---- init hidden from traj table (torch reshape(2,32,256) view), built LOCALLY ----
  for (int i = tid; i < 2*B*H; i += 384) {
    int l = i >> 13, bb = (i >> 8) & 31, h = i & 255;
    float v = a.traj[(size_t)a.labels[l*16 + (bb>>1)]*512 + (bb&1)*256 + h];
    Ash[l][bb*264 + h] = f2bf(v);
  }
  if (tid < 256) {   // own carries + publish h1-init into slot 1 (covered by flag 1)
    float v00 = a.traj[(size_t)a.labels[(pb>>1)]*512      + (pb&1)*256 + pgj];
    float v01 = a.traj[(size_t)a.labels[(pb>>1)]*512      + (pb&1)*256 + pgj+1];
    float v10 = a.traj[(size_t)a.labels[16 + (pb>>1)]*512 + (pb&1)*256 + pgj];
    float v11 = a.traj[(size_t)a.labels[16 + (pb>>1)]*512 + (pb&1)*256 + pgj+1];
    hc00 = v00; hc01 = v01; hc10 = v10; hc11 = v11;
    st_sc(&a.exch[1*8192 + ((jt*2 + 1)*32 + pb)*8 + pjp],
          (unsigned)f2bf(v10) | ((unsigned)f2bf(v11) << 16));
  }

  for (int p = 0; p <= T; ++p) {
    // ---- xp0 prefetch (hidden under poll + burst + MFMA) ----
    float2 xr, xz, xn;
    if (p < T && tid < 256) {
      const float* xp = a.xp0 + (size_t)(p*B + pb)*G3 + pgj;
      xr = *(const float2*)(xp);
      xz = *(const float2*)(xp + 256);
      xn = *(const float2*)(xp + 512);
    }
    // ---- stage exchanged h0/y0 and h1 into LDS: cheap flag poll, then ONE burst ----
    if (p) {
      const unsigned want = (unsigned)p;
      {
        unsigned it = 0;
        for (;;) {
          unsigned f = want;
          if (lane < 16) f = ld_sc32(&a.flags[(p & 1)*16 + lane]);
          if (__all((int)(f >= want))) break;
          if (++it > (1u << 22)) break;   // bounded: never hard-hang the queue
        }
      }
      const unsigned long long* src = (const unsigned long long*)a.exch + (size_t)(p & 1)*4096;
      unsigned long long v[11];
      #pragma unroll
      for (int k = 0; k < 11; ++k) {
        int i = tid + k*384;
        if (i < 4096) v[k] = ld_sc64(&src[i]);
      }
      #pragma unroll
      for (int k = 0; k < 11; ++k) {
        int i = tid + k*384;
        if (i < 4096) {
          int pp = i & 3, bb = (i >> 2) & 31, st = (i >> 7) & 1, jtp = (i >> 8) & 15;
          *(unsigned long long*)&Ash[st][bb*264 + jtp*16 + pp*4] = v[k];
        }
      }
    }
    __syncthreads();

    // ---- MFMA phase ----
    if (p < T) {            // L0, t = p: gates_h = h0 @ w_hh0^T
      f32x4 acc = (f32x4){0.f,0.f,0.f,0.f};
      #pragma unroll
      for (int kk = 0; kk < 8; ++kk) {
        s16x8 af = *(const s16x8*)&Ash[0][(mt*16 + fn)*264 + kk*32 + fq*8];
        acc = __builtin_amdgcn_mfma_f32_16x16x32_bf16(af, b0[kk], acc, 0, 0, 0);
      }
      #pragma unroll
      for (int i = 0; i < 4; ++i)
        gl0[(g*32 + mt*16 + fq*4 + i)*17 + fn] = acc[i];
    }
    if (p >= 1) {           // L1, t = p-1: x = y0 (Ash[0]), h = h1 (Ash[1])
      if (g < 2) {          // r,z: concat-K is valid
        f32x4 acc = (f32x4){0.f,0.f,0.f,0.f};
        #pragma unroll
        for (int kk = 0; kk < 8; ++kk) {
          s16x8 af = *(const s16x8*)&Ash[0][(mt*16 + fn)*264 + kk*32 + fq*8];
          acc = __builtin_amdgcn_mfma_f32_16x16x32_bf16(af, b1[kk], acc, 0, 0, 0);
        }
        #pragma unroll
        for (int kk = 0; kk < 8; ++kk) {
          s16x8 af = *(const s16x8*)&Ash[1][(mt*16 + fn)*264 + kk*32 + fq*8];
          acc = __builtin_amdgcn_mfma_f32_16x16x32_bf16(af, b1[8+kk], acc, 0, 0, 0);
        }
        #pragma unroll
        for (int i = 0; i < 4; ++i)
          gl1[(g*32 + mt*16 + fq*4 + i)*17 + fn] = acc[i];
      } else {              // n: x-part and h-part must stay separate (r * h-part)
        f32x4 ax = (f32x4){0.f,0.f,0.f,0.f}, ah = (f32x4){0.f,0.f,0.f,0.f};
        #pragma unroll
        for (int kk = 0; kk < 8; ++kk) {
          s16x8 afx = *(const s16x8*)&Ash[0][(mt*16 + fn)*264 + kk*32 + fq*8];
          s16x8 afh = *(const s16x8*)&Ash[1][(mt*16 + fn)*264 + kk*32 + fq*8];
          ax = __builtin_amdgcn_mfma_f32_16x16x32_bf16(afx, b1[kk],   ax, 0, 0, 0);
          ah = __builtin_amdgcn_mfma_f32_16x16x32_bf16(afh, b1[8+kk], ah, 0, 0, 0);
        }
        #pragma unroll
        for (int i = 0; i < 4; ++i) {
          gl1[(2*32 + mt*16 + fq*4 + i)*17 + fn] = ax[i];
          gl1[(3*32 + mt*16 + fq*4 + i)*17 + fn] = ah[i];
        }
      }
    }
    __syncthreads();

    // ---- pointwise update (fp32 carries in regs, publish payload to next slot) ----
    if (tid < 256) {
      const int slot = (p + 1) & 1;
      if (p < T) {          // L0, t = p
        float r0 = sigmoidf_(xr.x + gl0[pb*17+pj0]        + bh0r.x);
        float r1 = sigmoidf_(xr.y + gl0[pb*17+pj0+1]      + bh0r.y);
        float z0 = sigmoidf_(xz.x + gl0[(32+pb)*17+pj0]   + bh0z.x);
        float z1 = sigmoidf_(xz.y + gl0[(32+pb)*17+pj0+1] + bh0z.y);
        float n0 = tanhf_(xn.x + r0*(gl0[(64+pb)*17+pj0]   + bh0n.x));
        float n1 = tanhf_(xn.y + r1*(gl0[(64+pb)*17+pj0+1] + bh0n.y));
        float h0n = (1.f - z0)*n0 + z0*hc00;
        float h1n = (1.f - z1)*n1 + z1*hc01;
        hc00 = h0n; hc01 = h1n;
        st_sc(&a.exch[(size_t)slot*8192 + ((jt*2 + 0)*32 + pb)*8 + pjp],
              (unsigned)f2bf(h0n) | ((unsigned)f2bf(h1n) << 16));
      }
      if (p >= 1) {         // L1, t = p - 1
        const int t1 = p - 1;
        float r0 = sigmoidf_(gl1[pb*17+pj0]        + bi1r.x + bh1r.x);
        float r1 = sigmoidf_(gl1[pb*17+pj0+1]      + bi1r.y + bh1r.y);
        float z0 = sigmoidf_(gl1[(32+pb)*17+pj0]   + bi1z.x + bh1z.x);
        float z1 = sigmoidf_(gl1[(32+pb)*17+pj0+1] + bi1z.y + bh1z.y);
        float n0 = tanhf_(gl1[(64+pb)*17+pj0]   + bi1n.x + r0*(gl1[(96+pb)*17+pj0]   + bh1n.x));
        float n1 = tanhf_(gl1[(64+pb)*17+pj0+1] + bi1n.y + r1*(gl1[(96+pb)*17+pj0+1] + bh1n.y));
        float h0n = (1.f - z0)*n0 + z0*hc10;
        float h1n = (1.f - z1)*n1 + z1*hc11;
        hc10 = h0n; hc11 = h1n;
        if (p < T)
          st_sc(&a.exch[(size_t)slot*8192 + ((jt*2 + 1)*32 + pb)*8 + pjp],
                (unsigned)f2bf(h0n) | ((unsigned)f2bf(h1n) << 16));
        ((unsigned*)a.abf)[((size_t)(pb*T + t1)*H + pgj) >> 1] =
              (unsigned)f2bf(fmaxf(h0n,0.f)) | ((unsigned)f2bf(fmaxf(h1n,0.f)) << 16);
      }
    }
    // ---- publish flag: per-wave drain, block barrier, then one 4B flag store ----
    if (p < T) {
      asm volatile("s_waitcnt vmcnt(0)" ::: "memory");
      __syncthreads();
      if (tid == 0)
        st_sc(&a.flags[((p + 1) & 1)*16 + jt], (unsigned)(p + 1));
    }
  }
}

// ---------------- cast fc_w to bf16 (pad cols to 40064 with zero rows) ---------------
__global__ void castw_kernel(const float* __restrict__ fcw, unsigned short* __restrict__ wbf){
  int g = blockIdx.x*256 + threadIdx.x;   // float4 groups, NPADC*64 total
  if (g >= NPADC*64) return;
  int row = g >> 6;
  ushort4 o;
  if (row < NOUTC) {
    float4 v = ((const float4*)fcw)[g];
    o.x=f2bf(v.x); o.y=f2bf(v.y); o.z=f2bf(v.z); o.w=f2bf(v.w);
  } else { o.x=0; o.y=0; o.z=0; o.w=0; }
  ((ushort4*)wbf)[g] = o;
}

// ---------------- K4: bf16 MFMA GEMM + fused per-tile logsumexp partials -------------
__global__ void __launch_bounds__(256) gemm_kernel(const unsigned short* __restrict__ Abf,
                                                   const unsigned short* __restrict__ Wbf,
                                                   const float* __restrict__ fc_b,
                                                   float* __restrict__ dout,
                                                   float2* __restrict__ part)
{
  __shared__ unsigned short As[128*32];
  __shared__ unsigned short Ws[128*32];
  const int m0 = blockIdx.x * 128;
  const int n0 = blockIdx.y * 128;
  const int tid = threadIdx.x;
  const int lane = tid & 63;
  const int wv = tid >> 6;
  f32x4 acc[2][8];
  #pragma unroll
  for (int i=0;i<2;i++)
    #pragma unroll
    for(int jx=0;jx<8;jx++) acc[i][jx] = (f32x4){0.f,0.f,0.f,0.f};

  const int srow = tid >> 2;
  const int skoff = (tid & 3) * 8;
  const unsigned short* aptr = Abf + (size_t)(m0 + srow)*256 + skoff;
  const unsigned short* wptr = Wbf + (size_t)(n0 + srow)*256 + skoff;
  unsigned short* asd = &As[tid*8];
  unsigned short* wsd = &Ws[tid*8];

  const int fr = lane & 15;
  const int fk = (lane >> 4) * 8;

  for (int kk = 0; kk < 256; kk += 32) {
    gl_lds16(aptr + kk,            asd);
    gl_lds16(aptr + 64*256 + kk,   asd + 64*32);
    gl_lds16(wptr + kk,            wsd);
    gl_lds16(wptr + 64*256 + kk,   wsd + 64*32);
    __syncthreads();
    s16x8 a0 = *(const s16x8*)&As[(wv*32 + fr)*32 + fk];
    s16x8 a1 = *(const s16x8*)&As[(wv*32 + 16 + fr)*32 + fk];
    #pragma unroll
    for (int ct = 0; ct < 8; ++ct) {
      s16x8 bfr = *(const s16x8*)&Ws[(ct*16 + fr)*32 + fk];
      acc[0][ct] = __builtin_amdgcn_mfma_f32_16x16x32_bf16(a0, bfr, acc[0][ct], 0, 0, 0);
      acc[1][ct] = __builtin_amdgcn_mfma_f32_16x16x32_bf16(a1, bfr, acc[1][ct], 0, 0, 0);
    }
    __syncthreads();
  }

  const int quad = lane >> 4;
  // fold bias into acc (final logits), then store
  #pragma unroll
  for (int rt = 0; rt < 2; ++rt) {
    #pragma unroll
    for (int ct = 0; ct < 8; ++ct) {
      int col = n0 + ct*16 + fr;
      float bias = (col < NOUTC) ? fc_b[col] : 0.f;
      #pragma unroll
      for (int i = 0; i < 4; ++i) acc[rt][ct][i] += bias;
      if (col < NOUTC) {
        #pragma unroll
        for (int i = 0; i < 4; ++i) {
          int row2 = m0 + wv*32 + rt*16 + quad*4 + i;
          float v = acc[rt][ct][i];
          if (col < OUT) dout[(size_t)row2*OUT + col] = v;
          else dout[(size_t)OUT*B*T + (size_t)row2*TD + (col - OUT)] = v;
        }
      }
    }
  }
  // per-tile {rowmax, sumexp} over loc cols (col < OUT) -> tiny stats pass
  #pragma unroll
  for (int rt = 0; rt < 2; ++rt) {
    #pragma unroll
    for (int i = 0; i < 4; ++i) {
      float mx = -INFINITY;
      #pragma unroll
      for (int ct = 0; ct < 8; ++ct)
        if (n0 + ct*16 + fr < OUT) mx = fmaxf(mx, acc[rt][ct][i]);
      #pragma unroll
      for (int off = 1; off < 16; off <<= 1) mx = fmaxf(mx, __shfl_xor(mx, off));
      float sx = 0.f;
      #pragma unroll
      for (int ct = 0; ct < 8; ++ct)
        if (n0 + ct*16 + fr < OUT) sx += __expf(acc[rt][ct][i] - mx);
      #pragma unroll
      for (int off = 1; off < 16; off <<= 1) sx += __shfl_xor(sx, off);
      if (fr == 0) {
        int row2 = m0 + wv*32 + rt*16 + quad*4 + i;
        part[(size_t)row2*NTP + (n0 >> 7)] = make_float2(mx, sx);
      }
    }
  }
}

// ---------------- K5: reduce 313 per-tile partials per row -> logz -------------------
__global__ void stats_kernel(const float2* __restrict__ part, float* __restrict__ logz){
  const int r = blockIdx.x;
  const int lane = threadIdx.x;   // 64
  float m = -INFINITY, s = 0.f;
  for (int i = lane; i < NT; i += 64) {
    float2 pp = part[(size_t)r*NTP + i];
    float nm = fmaxf(m, pp.x);
    s = s*__expf(m - nm) + pp.y*__expf(pp.x - nm);
    m = nm;
  }
  #pragma unroll
  for (int off = 1; off < 64; off <<= 1) {
    float m2 = __shfl_xor(m, off);
    float s2 = __shfl_xor(s, off);
    float nm = fmaxf(m, m2);
    s = s*__expf(m - nm) + s2*__expf(m2 - nm);
    m = nm;
  }
  if (lane == 0) logz[r] = m + logf(s);
}

// ---------------- K6: in-place normalize loc ----------------------------------------
__global__ void norm_kernel(float* __restrict__ dout, const float* __restrict__ logz){
  size_t i = (size_t)blockIdx.x*256 + threadIdx.x;   // float4 index
  if (i >= (size_t)B*T*OUT/4) return;
  int r = (int)(i / (OUT/4));
  float lz = logz[r];
  float4* p = (float4*)dout + i;
  float4 v = *p;
  v.x -= lz; v.y -= lz; v.z -= lz; v.w -= lz;
  *p = v;
}

// ---------------- K7: tm log_softmax (48 wide), in place -----------------------------
__global__ void tm_kernel(float* __restrict__ dout){
  const int r = blockIdx.x;
  const int lane = threadIdx.x;   // 64
  float* base = dout + (size_t)OUT*B*T + (size_t)r*TD;
  float v = (lane < TD) ? base[lane] : -INFINITY;
  float m = v;
  #pragma unroll
  for (int off=32; off; off>>=1) m = fmaxf(m, __shfl_xor(m, off));
  float e = (lane < TD) ? __expf(v - m) : 0.f;
  float s = e;
  #pragma unroll
  for (int off=32; off; off>>=1) s += __shfl_xor(s, off);
  float lz = m + logf(s);
  if (lane < TD) base[lane] = v - lz;
}

extern "C" void kernel_launch(void* const* d_in, const int* in_sizes, int n_in,
                              void* d_out, int out_size, void* d_ws, size_t ws_size,
                              hipStream_t stream)
{
  const int*   locations = (const int*)d_in[0];
  const int*   times     = (const int*)d_in[1];
  const int*   labels    = (const int*)d_in[2];
  const float* embed     = (const float*)d_in[3];
  const float* traj      = (const float*)d_in[4];
  const float* fc_w      = (const float*)d_in[5];
  const float* fc_b      = (const float*)d_in[6];
  const float* w_ih0     = (const float*)d_in[7];
  const float* w_hh0     = (const float*)d_in[8];
  const float* b_ih0     = (const float*)d_in[9];
  const float* b_hh0     = (const float*)d_in[10];
  const float* w_ih1     = (const float*)d_in[11];
  const float* w_hh1     = (const float*)d_in[12];
  const float* b_ih1     = (const float*)d_in[13];
  const float* b_hh1     = (const float*)d_in[14];
  float* out = (float*)d_out;
  char* ws = (char*)d_ws;

  float* xp0            = (float*)(ws);                    // 4,718,592 B (gru phase)
  float2* part          = (float2*)(ws);                   // 3,932,160 B (gemm phase, reuses xp0)
  unsigned* exch        = (unsigned*)(ws + 4718592);       //    65,536
  unsigned* flags       = (unsigned*)(ws + 4784128);       //       256 (padded)
  float* logz           = (float*)(ws + 4784384);          //     6,144
  unsigned short* abf   = (unsigned short*)(ws + 4790528); //   786,432
  unsigned short* wbf   = (unsigned short*)(ws + 5576960); // 20,512,768
  float* wT             = (float*)(ws + 26089728);         //   393,216 -> ~26.5 MB

  castw_kernel<<<dim3((NPADC*64 + 255)/256), dim3(256), 0, stream>>>(fc_w, wbf);
  wt_kernel<<<dim3((E*G3 + 255)/256), dim3(256), 0, stream>>>(w_ih0, wT, flags);
  xp0_kernel<<<dim3(96), dim3(256), 0, stream>>>(locations, times, embed, wT, w_ih0, b_ih0, xp0);

  GruArgs ga{xp0, traj, labels, w_hh0, b_hh0, w_ih1, w_hh1, b_ih1, b_hh1,
             exch, flags, abf};
  void* kargs[] = { &ga };
  hipLaunchCooperativeKernel((void*)gru_kernel, dim3(16), dim3(384), kargs, 0, stream);

  gemm_kernel<<<dim3(12, 313), dim3(256), 0, stream>>>(abf, wbf, fc_b, out, part);
  stats_kernel<<<dim3(B*T), dim3(64), 0, stream>>>(part, logz);
  norm_kernel<<<dim3((B*T*OUT/4 + 255)/256), dim3(256), 0, stream>>>(out, logz);
  tm_kernel<<<dim3(B*T), dim3(64), 0, stream>>>(out);
}

// Round 4
// 719.358 us; speedup vs baseline: 1.1509x; 1.0011x over previous
//
#include <hip/hip_runtime.h>
#include <math.h>

typedef __attribute__((ext_vector_type(4))) float f32x4;
typedef __attribute__((ext_vector_type(8))) short s16x8;

constexpr int B = 32, T = 48, H = 256, E = 128, TD = 48;
constexpr int OUT = 40000, NOUTC = 40048, NPADC = 40064;
constexpr int G3 = 768, DIN = 176;
constexpr int NT = 313, NTP = 320;   // fc col-tiles (40064/128) for stats partials

__device__ __forceinline__ float sigmoidf_(float x){ return 1.f/(1.f+__expf(-x)); }
__device__ __forceinline__ float tanhf_(float x){
  float e = __expf(2.f*x);            // inf-safe: x>>0 -> 1, x<<0 -> -1
  return 1.f - 2.f/(e + 1.f);
}
__device__ __forceinline__ unsigned short f2bf(float f){
  unsigned int u = __float_as_uint(f);
  u += 0x7fffu + ((u>>16)&1u);   // RNE
  return (unsigned short)(u>>16);
}
__device__ __forceinline__ s16x8 pack8(float4 u, float4 v){
  s16x8 r;
  r[0]=(short)f2bf(u.x); r[1]=(short)f2bf(u.y); r[2]=(short)f2bf(u.z); r[3]=(short)f2bf(u.w);
  r[4]=(short)f2bf(v.x); r[5]=(short)f2bf(v.y); r[6]=(short)f2bf(v.z); r[7]=(short)f2bf(v.w);
  return r;
}
__device__ __forceinline__ void gl_lds16(const unsigned short* g, unsigned short* l){
  __builtin_amdgcn_global_load_lds((const __attribute__((address_space(1))) void*)g,
                                   (__attribute__((address_space(3))) void*)l, 16, 0, 0);
}
// system-scope (bypass per-XCD L2) relaxed ops; these lower to plain flagged
// vector loads/stores -> full wave coalescing, unlike RMW atomics.
__device__ __forceinline__ void st_sc(unsigned* p, unsigned v){
  __hip_atomic_store(p, v, __ATOMIC_RELAXED, __HIP_MEMORY_SCOPE_SYSTEM);
}
__device__ __forceinline__ unsigned ld_sc32(const unsigned* p){
  return __hip_atomic_load((unsigned*)p, __ATOMIC_RELAXED, __HIP_MEMORY_SCOPE_SYSTEM);
}
__device__ __forceinline__ unsigned long long ld_sc64(const unsigned long long* p){
  return __hip_atomic_load((unsigned long long*)p, __ATOMIC_RELAXED, __HIP_MEMORY_SCOPE_SYSTEM);
}

// ------- transpose w_ih0[:, :128] -> wT[e][g]; also zero the 32 flag words ----------
__global__ void wt_kernel(const float* __restrict__ w_ih0, float* __restrict__ wT,
                          unsigned* __restrict__ flags){
  int i = blockIdx.x*256 + threadIdx.x;       // over 128*768
  if (blockIdx.x == 0 && threadIdx.x < 32)
    __hip_atomic_store(&flags[threadIdx.x], 0u, __ATOMIC_RELAXED, __HIP_MEMORY_SCOPE_SYSTEM);
  if (i >= E*G3) return;
  int e = i / G3, g = i % G3;
  wT[i] = w_ih0[g*DIN + e];
}

// ---------------- K1: xp0[t*B+b][g] = emb(loc)·w_ih0[g,:128] + w_ih0[g,128+time] + b_ih0[g]
__global__ void xp0_kernel(const int* __restrict__ locations, const int* __restrict__ times,
                           const float* __restrict__ embed, const float* __restrict__ wT,
                           const float* __restrict__ w_ih0, const float* __restrict__ b_ih0,
                           float* __restrict__ xp0)
{
  __shared__ float emb_s[16][E];
  __shared__ int tm_s[16];
  const int r0 = blockIdx.x * 16;
  const int tid = threadIdx.x;
  for (int i = tid; i < 16*E; i += 256) {
    int p = i >> 7, e = i & 127;
    int r = r0 + p; int t = r >> 5, b = r & 31;
    emb_s[p][e] = embed[(size_t)locations[b*T + t]*E + e];
  }
  if (tid < 16) {
    int r = r0 + tid; int t = r >> 5, b = r & 31;
    tm_s[tid] = times[b*T + t];
  }
  __syncthreads();
  const int g = tid;  // gate rows g, g+256, g+512
  float acc[16][3];
  #pragma unroll
  for (int p=0;p<16;p++){acc[p][0]=0.f;acc[p][1]=0.f;acc[p][2]=0.f;}
  for (int e = 0; e < E; e += 4) {
    float w0_[4], w1_[4], w2_[4];
    #pragma unroll
    for (int i=0;i<4;i++){
      w0_[i]=wT[(e+i)*G3 + g];
      w1_[i]=wT[(e+i)*G3 + 256 + g];
      w2_[i]=wT[(e+i)*G3 + 512 + g];
    }
    #pragma unroll
    for (int p=0;p<16;p++){
      float4 ev = *(const float4*)&emb_s[p][e];
      acc[p][0] += ev.x*w0_[0]+ev.y*w0_[1]+ev.z*w0_[2]+ev.w*w0_[3];
      acc[p][1] += ev.x*w1_[0]+ev.y*w1_[1]+ev.z*w1_[2]+ev.w*w1_[3];
      acc[p][2] += ev.x*w2_[0]+ev.y*w2_[1]+ev.z*w2_[2]+ev.w*w2_[3];
    }
  }
  #pragma unroll
  for (int p=0;p<16;p++){
    int r = r0+p; int tt = tm_s[p];
    xp0[(size_t)r*G3 + g]       = acc[p][0] + b_ih0[g]     + w_ih0[g*DIN       + E + tt];
    xp0[(size_t)r*G3 + 256 + g] = acc[p][1] + b_ih0[g+256] + w_ih0[(g+256)*DIN + E + tt];
    xp0[(size_t)r*G3 + 512 + g] = acc[p][2] + b_ih0[g+512] + w_ih0[(g+512)*DIN + E + tt];
  }
}

// ---------------- K2: cooperative 2-layer GRU, MFMA recurrence, weights in VGPRs -----
// 16 blocks x 384 threads. Cross-block h exchange: bulk payload (pure 32KB/step) via
// coalesced system-scope loads issued ONCE, gated by a per-block flag in ONE 64B line
// (flag stored after per-wave vmcnt(0) drain + block barrier => payload guaranteed
// visible when flag observed). Polling traffic ~100B/block/round -> no fabric storm.
struct GruArgs {
  const float* xp0; const float* traj; const int* labels;
  const float* w_hh0; const float* b_hh0;
  const float* w_ih1; const float* w_hh1; const float* b_ih1; const float* b_hh1;
  unsigned* exch;     // [parity 2][jt 16][state 2][b 32][jp 8] u32 = {2x bf16}
  unsigned* flags;    // [parity 2][16] u32 step stamps (one 64B line per parity)
  unsigned short* abf;
};

__global__ void __launch_bounds__(384, 2) gru_kernel(GruArgs a)
{
  __shared__ unsigned short Ash[2][32*264]; // [0]=h0/y0, [1]=h1 bf16, row stride 264
  __shared__ float gl0[3*32*17];            // L0 gate pre-acts (hr,hz,hn)
  __shared__ float gl1[4*32*17];            // L1 gate pre-acts (r,z,nx,nh)
  const int tid  = threadIdx.x;
  const int jt   = blockIdx.x;
  const int wv   = tid >> 6;
  const int lane = tid & 63;
  const int g    = wv % 3, mt = wv / 3;
  const int fn   = lane & 15;
  const int fq   = lane >> 4;

  // ---- B fragments (weights) loaded ONCE into registers ----
  const int row = g*256 + jt*16 + fn;
  s16x8 b0[8], b1[16];
  #pragma unroll
  for (int kk = 0; kk < 8; ++kk) {
    const float* p0 = a.w_hh0 + (size_t)row*H + kk*32 + fq*8;
    const float* p1 = a.w_ih1 + (size_t)row*H + kk*32 + fq*8;
    const float* p2 = a.w_hh1 + (size_t)row*H + kk*32 + fq*8;
    b0[kk]    = pack8(*(const float4*)p0, *(const float4*)(p0+4));
    b1[kk]    = pack8(*(const float4*)p1, *(const float4*)(p1+4));
    b1[kk+8]  = pack8(*(const float4*)p2, *(const float4*)(p2+4));
  }

  // ---- pointwise thread identity, bias preload, fp32 carries in REGISTERS ----
  const int pb = tid >> 3, pjp = tid & 7, pj0 = pjp*2, pgj = jt*16 + pj0;
  float2 bh0r, bh0z, bh0n, bi1r, bi1z, bi1n, bh1r, bh1z, bh1n;
  float hc00 = 0.f, hc01 = 0.f, hc10 = 0.f, hc11 = 0.f;
  if (tid < 256) {
    bh0r = *(const float2*)&a.b_hh0[pgj];
    bh0z = *(const float2*)&a.b_hh0[256+pgj];
    bh0n = *(const float2*)&a.b_hh0[512+pgj];
    bi1r = *(const float2*)&a.b_ih1[pgj];
    bi1z = *(const float2*)&a.b_ih1[256+pgj];
    bi1n = *(const float2*)&a.b_ih1[512+pgj];
    bh1r = *(const float2*)&a.b_hh1[pgj];
    bh1z = *(const float2*)&a.b_hh1[256+pgj];
    bh1n = *(const float2*)&a.b_hh1[512+pgj];
  }

  // ---- init hidden from traj table (torch reshape(2,32,256) view), built LOCALLY ----
  for (int i = tid; i < 2*B*H; i += 384) {
    int l = i >> 13, bb = (i >> 8) & 31, h = i & 255;
    float v = a.traj[(size_t)a.labels[l*16 + (bb>>1)]*512 + (bb&1)*256 + h];
    Ash[l][bb*264 + h] = f2bf(v);
  }
  if (tid < 256) {   // own carries + publish h1-init into slot 1 (covered by flag 1)
    float v00 = a.traj[(size_t)a.labels[(pb>>1)]*512      + (pb&1)*256 + pgj];
    float v01 = a.traj[(size_t)a.labels[(pb>>1)]*512      + (pb&1)*256 + pgj+1];
    float v10 = a.traj[(size_t)a.labels[16 + (pb>>1)]*512 + (pb&1)*256 + pgj];
    float v11 = a.traj[(size_t)a.labels[16 + (pb>>1)]*512 + (pb&1)*256 + pgj+1];
    hc00 = v00; hc01 = v01; hc10 = v10; hc11 = v11;
    st_sc(&a.exch[1*8192 + ((jt*2 + 1)*32 + pb)*8 + pjp],
          (unsigned)f2bf(v10) | ((unsigned)f2bf(v11) << 16));
  }

  for (int p = 0; p <= T; ++p) {
    // ---- xp0 prefetch (hidden under poll + burst + MFMA) ----
    float2 xr, xz, xn;
    if (p < T && tid < 256) {
      const float* xp = a.xp0 + (size_t)(p*B + pb)*G3 + pgj;
      xr = *(const float2*)(xp);
      xz = *(const float2*)(xp + 256);
      xn = *(const float2*)(xp + 512);
    }
    // ---- stage exchanged h0/y0 and h1 into LDS: cheap flag poll, then ONE burst ----
    if (p) {
      const unsigned want = (unsigned)p;
      {
        unsigned it = 0;
        for (;;) {
          unsigned f = want;
          if (lane < 16) f = ld_sc32(&a.flags[(p & 1)*16 + lane]);
          if (__all((int)(f >= want))) break;
          if (++it > (1u << 22)) break;   // bounded: never hard-hang the queue
        }
      }
      const unsigned long long* src = (const unsigned long long*)a.exch + (size_t)(p & 1)*4096;
      unsigned long long v[11];
      #pragma unroll
      for (int k = 0; k < 11; ++k) {
        int i = tid + k*384;
        if (i < 4096) v[k] = ld_sc64(&src[i]);
      }
      #pragma unroll
      for (int k = 0; k < 11; ++k) {
        int i = tid + k*384;
        if (i < 4096) {
          int pp = i & 3, bb = (i >> 2) & 31, st = (i >> 7) & 1, jtp = (i >> 8) & 15;
          *(unsigned long long*)&Ash[st][bb*264 + jtp*16 + pp*4] = v[k];
        }
      }
    }
    __syncthreads();

    // ---- MFMA phase ----
    if (p < T) {            // L0, t = p: gates_h = h0 @ w_hh0^T
      f32x4 acc = (f32x4){0.f,0.f,0.f,0.f};
      #pragma unroll
      for (int kk = 0; kk < 8; ++kk) {
        s16x8 af = *(const s16x8*)&Ash[0][(mt*16 + fn)*264 + kk*32 + fq*8];
        acc = __builtin_amdgcn_mfma_f32_16x16x32_bf16(af, b0[kk], acc, 0, 0, 0);
      }
      #pragma unroll
      for (int i = 0; i < 4; ++i)
        gl0[(g*32 + mt*16 + fq*4 + i)*17 + fn] = acc[i];
    }
    if (p >= 1) {           // L1, t = p-1: x = y0 (Ash[0]), h = h1 (Ash[1])
      if (g < 2) {          // r,z: concat-K is valid
        f32x4 acc = (f32x4){0.f,0.f,0.f,0.f};
        #pragma unroll
        for (int kk = 0; kk < 8; ++kk) {
          s16x8 af = *(const s16x8*)&Ash[0][(mt*16 + fn)*264 + kk*32 + fq*8];
          acc = __builtin_amdgcn_mfma_f32_16x16x32_bf16(af, b1[kk], acc, 0, 0, 0);
        }
        #pragma unroll
        for (int kk = 0; kk < 8; ++kk) {
          s16x8 af = *(const s16x8*)&Ash[1][(mt*16 + fn)*264 + kk*32 + fq*8];
          acc = __builtin_amdgcn_mfma_f32_16x16x32_bf16(af, b1[8+kk], acc, 0, 0, 0);
        }
        #pragma unroll
        for (int i = 0; i < 4; ++i)
          gl1[(g*32 + mt*16 + fq*4 + i)*17 + fn] = acc[i];
      } else {              // n: x-part and h-part must stay separate (r * h-part)
        f32x4 ax = (f32x4){0.f,0.f,0.f,0.f}, ah = (f32x4){0.f,0.f,0.f,0.f};
        #pragma unroll
        for (int kk = 0; kk < 8; ++kk) {
          s16x8 afx = *(const s16x8*)&Ash[0][(mt*16 + fn)*264 + kk*32 + fq*8];
          s16x8 afh = *(const s16x8*)&Ash[1][(mt*16 + fn)*264 + kk*32 + fq*8];
          ax = __builtin_amdgcn_mfma_f32_16x16x32_bf16(afx, b1[kk],   ax, 0, 0, 0);
          ah = __builtin_amdgcn_mfma_f32_16x16x32_bf16(afh, b1[8+kk], ah, 0, 0, 0);
        }
        #pragma unroll
        for (int i = 0; i < 4; ++i) {
          gl1[(2*32 + mt*16 + fq*4 + i)*17 + fn] = ax[i];
          gl1[(3*32 + mt*16 + fq*4 + i)*17 + fn] = ah[i];
        }
      }
    }
    __syncthreads();

    // ---- pointwise update (fp32 carries in regs, publish payload to next slot) ----
    float relu0 = 0.f, relu1 = 0.f;
    if (tid < 256) {
      const int slot = (p + 1) & 1;
      if (p < T) {          // L0, t = p
        float r0 = sigmoidf_(xr.x + gl0[pb*17+pj0]        + bh0r.x);
        float r1 = sigmoidf_(xr.y + gl0[pb*17+pj0+1]      + bh0r.y);
        float z0 = sigmoidf_(xz.x + gl0[(32+pb)*17+pj0]   + bh0z.x);
        float z1 = sigmoidf_(xz.y + gl0[(32+pb)*17+pj0+1] + bh0z.y);
        float n0 = tanhf_(xn.x + r0*(gl0[(64+pb)*17+pj0]   + bh0n.x));
        float n1 = tanhf_(xn.y + r1*(gl0[(64+pb)*17+pj0+1] + bh0n.y));
        float h0n = (1.f - z0)*n0 + z0*hc00;
        float h1n = (1.f - z1)*n1 + z1*hc01;
        hc00 = h0n; hc01 = h1n;
        st_sc(&a.exch[(size_t)slot*8192 + ((jt*2 + 0)*32 + pb)*8 + pjp],
              (unsigned)f2bf(h0n) | ((unsigned)f2bf(h1n) << 16));
      }
      if (p >= 1) {         // L1, t = p - 1
        float r0 = sigmoidf_(gl1[pb*17+pj0]        + bi1r.x + bh1r.x);
        float r1 = sigmoidf_(gl1[pb*17+pj0+1]      + bi1r.y + bh1r.y);
        float z0 = sigmoidf_(gl1[(32+pb)*17+pj0]   + bi1z.x + bh1z.x);
        float z1 = sigmoidf_(gl1[(32+pb)*17+pj0+1] + bi1z.y + bh1z.y);
        float n0 = tanhf_(gl1[(64+pb)*17+pj0]   + bi1n.x + r0*(gl1[(96+pb)*17+pj0]   + bh1n.x));
        float n1 = tanhf_(gl1[(64+pb)*17+pj0+1] + bi1n.y + r1*(gl1[(96+pb)*17+pj0+1] + bh1n.y));
        float h0n = (1.f - z0)*n0 + z0*hc10;
        float h1n = (1.f - z1)*n1 + z1*hc11;
        hc10 = h0n; hc11 = h1n;
        if (p < T)
          st_sc(&a.exch[(size_t)slot*8192 + ((jt*2 + 1)*32 + pb)*8 + pjp],
                (unsigned)f2bf(h0n) | ((unsigned)f2bf(h1n) << 16));
        relu0 = fmaxf(h0n, 0.f); relu1 = fmaxf(h1n, 0.f);
      }
    }
    // ---- publish flag: per-wave drain, block barrier, then one 4B flag store ----
    if (p < T) {
      asm volatile("s_waitcnt vmcnt(0)" ::: "memory");
      __syncthreads();
      if (tid == 0)
        st_sc(&a.flags[((p + 1) & 1)*16 + jt], (unsigned)(p + 1));
    }
    // ---- abf relu store AFTER the drain/flag (off the exchange critical path) ----
    if (p >= 1 && tid < 256) {
      ((unsigned*)a.abf)[((size_t)(pb*T + (p - 1))*H + pgj) >> 1] =
            (unsigned)f2bf(relu0) | ((unsigned)f2bf(relu1) << 16);
    }
  }
}

// ---------------- cast fc_w to bf16 (pad cols to 40064 with zero rows) ---------------
__global__ void castw_kernel(const float* __restrict__ fcw, unsigned short* __restrict__ wbf){
  int g = blockIdx.x*256 + threadIdx.x;   // float4 groups, NPADC*64 total
  if (g >= NPADC*64) return;
  int row = g >> 6;
  ushort4 o;
  if (row < NOUTC) {
    float4 v = ((const float4*)fcw)[g];
    o.x=f2bf(v.x); o.y=f2bf(v.y); o.z=f2bf(v.z); o.w=f2bf(v.w);
  } else { o.x=0; o.y=0; o.z=0; o.w=0; }
  ((ushort4*)wbf)[g] = o;
}

// ---------------- K4: bf16 MFMA FC, two passes, double-buffered staging --------------
// WRITE=0: compute logits, emit per-(row, n-tile) {rowmax, sumexp} partials only
//          (NO 246 MB raw-logit write).
// WRITE=1: recompute identical logits (deterministic MFMA), write loc logits already
//          normalized (v - logz[row]) and raw tm logits. norm_kernel eliminated.
template <int WRITE>
__global__ void __launch_bounds__(256) fc_kernel(const unsigned short* __restrict__ Abf,
                                                 const unsigned short* __restrict__ Wbf,
                                                 const float* __restrict__ fc_b,
                                                 const float* __restrict__ logz,
                                                 float* __restrict__ dout,
                                                 float2* __restrict__ part)
{
  __shared__ unsigned short As[2][128*32];
  __shared__ unsigned short Ws[2][128*32];
  const int m0 = blockIdx.x * 128;
  const int n0 = blockIdx.y * 128;
  const int tid = threadIdx.x;
  const int lane = tid & 63;
  const int wv = tid >> 6;
  f32x4 acc[2][8];
  #pragma unroll
  for (int i=0;i<2;i++)
    #pragma unroll
    for(int jx=0;jx<8;jx++) acc[i][jx] = (f32x4){0.f,0.f,0.f,0.f};

  const int srow = tid >> 2;
  const int skoff = (tid & 3) * 8;
  const unsigned short* aptr = Abf + (size_t)(m0 + srow)*256 + skoff;
  const unsigned short* wptr = Wbf + (size_t)(n0 + srow)*256 + skoff;

  const int fr = lane & 15;
  const int fk = (lane >> 4) * 8;

  // stage K-chunk kc (32 wide) into LDS buffer bb
  auto stage = [&](int kc, int bb) {
    unsigned short* asd = &As[bb][tid*8];
    unsigned short* wsd = &Ws[bb][tid*8];
    gl_lds16(aptr + kc*32,          asd);
    gl_lds16(aptr + 64*256 + kc*32, asd + 64*32);
    gl_lds16(wptr + kc*32,          wsd);
    gl_lds16(wptr + 64*256 + kc*32, wsd + 64*32);
  };

  stage(0, 0);
  asm volatile("s_waitcnt vmcnt(0)" ::: "memory");
  __syncthreads();
  int cur = 0;
  for (int kc = 0; kc < 8; ++kc) {
    if (kc < 7) stage(kc + 1, cur ^ 1);   // next chunk in flight under the MFMAs
    s16x8 a0 = *(const s16x8*)&As[cur][(wv*32 + fr)*32 + fk];
    s16x8 a1 = *(const s16x8*)&As[cur][(wv*32 + 16 + fr)*32 + fk];
    #pragma unroll
    for (int ct = 0; ct < 8; ++ct) {
      s16x8 bfr = *(const s16x8*)&Ws[cur][(ct*16 + fr)*32 + fk];
      acc[0][ct] = __builtin_amdgcn_mfma_f32_16x16x32_bf16(a0, bfr, acc[0][ct], 0, 0, 0);
      acc[1][ct] = __builtin_amdgcn_mfma_f32_16x16x32_bf16(a1, bfr, acc[1][ct], 0, 0, 0);
    }
    asm volatile("s_waitcnt vmcnt(0)" ::: "memory");
    __syncthreads();
    cur ^= 1;
  }

  const int quad = lane >> 4;
  // fold bias into acc (final logits)
  #pragma unroll
  for (int rt = 0; rt < 2; ++rt) {
    #pragma unroll
    for (int ct = 0; ct < 8; ++ct) {
      int col = n0 + ct*16 + fr;
      float bias = (col < NOUTC) ? fc_b[col] : 0.f;
      #pragma unroll
      for (int i = 0; i < 4; ++i) acc[rt][ct][i] += bias;
    }
  }

  if (WRITE) {
    #pragma unroll
    for (int rt = 0; rt < 2; ++rt) {
      #pragma unroll
      for (int i = 0; i < 4; ++i) {
        int row2 = m0 + wv*32 + rt*16 + quad*4 + i;
        float lz = logz[row2];
        #pragma unroll
        for (int ct = 0; ct < 8; ++ct) {
          int col = n0 + ct*16 + fr;
          if (col < OUT) dout[(size_t)row2*OUT + col] = acc[rt][ct][i] - lz;
          else if (col < NOUTC)
            dout[(size_t)OUT*B*T + (size_t)row2*TD + (col - OUT)] = acc[rt][ct][i];
        }
      }
    }
  } else {
    // per-tile {rowmax, sumexp} over loc cols (col < OUT) -> tiny stats pass
    #pragma unroll
    for (int rt = 0; rt < 2; ++rt) {
      #pragma unroll
      for (int i = 0; i < 4; ++i) {
        float mx = -INFINITY;
        #pragma unroll
        for (int ct = 0; ct < 8; ++ct)
          if (n0 + ct*16 + fr < OUT) mx = fmaxf(mx, acc[rt][ct][i]);
        #pragma unroll
        for (int off = 1; off < 16; off <<= 1) mx = fmaxf(mx, __shfl_xor(mx, off));
        float sx = 0.f;
        #pragma unroll
        for (int ct = 0; ct < 8; ++ct)
          if (n0 + ct*16 + fr < OUT) sx += __expf(acc[rt][ct][i] - mx);
        #pragma unroll
        for (int off = 1; off < 16; off <<= 1) sx += __shfl_xor(sx, off);
        if (fr == 0) {
          int row2 = m0 + wv*32 + rt*16 + quad*4 + i;
          part[(size_t)row2*NTP + (n0 >> 7)] = make_float2(mx, sx);
        }
      }
    }
  }
}

// ---------------- K5: reduce 313 per-tile partials per row -> logz -------------------
__global__ void stats_kernel(const float2* __restrict__ part, float* __restrict__ logz){
  const int r = blockIdx.x;
  const int lane = threadIdx.x;   // 64
  float m = -INFINITY, s = 0.f;
  for (int i = lane; i < NT; i += 64) {
    float2 pp = part[(size_t)r*NTP + i];
    float nm = fmaxf(m, pp.x);
    s = s*__expf(m - nm) + pp.y*__expf(pp.x - nm);
    m = nm;
  }
  #pragma unroll
  for (int off = 1; off < 64; off <<= 1) {
    float m2 = __shfl_xor(m, off);
    float s2 = __shfl_xor(s, off);
    float nm = fmaxf(m, m2);
    s = s*__expf(m - nm) + s2*__expf(m2 - nm);
    m = nm;
  }
  if (lane == 0) logz[r] = m + logf(s);
}

// ---------------- K7: tm log_softmax (48 wide), in place -----------------------------
__global__ void tm_kernel(float* __restrict__ dout){
  const int r = blockIdx.x;
  const int lane = threadIdx.x;   // 64
  float* base = dout + (size_t)OUT*B*T + (size_t)r*TD;
  float v = (lane < TD) ? base[lane] : -INFINITY;
  float m = v;
  #pragma unroll
  for (int off=32; off; off>>=1) m = fmaxf(m, __shfl_xor(m, off));
  float e = (lane < TD) ? __expf(v - m) : 0.f;
  float s = e;
  #pragma unroll
  for (int off=32; off; off>>=1) s += __shfl_xor(s, off);
  float lz = m + logf(s);
  if (lane < TD) base[lane] = v - lz;
}

extern "C" void kernel_launch(void* const* d_in, const int* in_sizes, int n_in,
                              void* d_out, int out_size, void* d_ws, size_t ws_size,
                              hipStream_t stream)
{
  const int*   locations = (const int*)d_in[0];
  const int*   times     = (const int*)d_in[1];
  const int*   labels    = (const int*)d_in[2];
  const float* embed     = (const float*)d_in[3];
  const float* traj      = (const float*)d_in[4];
  const float* fc_w      = (const float*)d_in[5];
  const float* fc_b      = (const float*)d_in[6];
  const float* w_ih0     = (const float*)d_in[7];
  const float* w_hh0     = (const float*)d_in[8];
  const float* b_ih0     = (const float*)d_in[9];
  const float* b_hh0     = (const float*)d_in[10];
  const float* w_ih1     = (const float*)d_in[11];
  const float* w_hh1     = (const float*)d_in[12];
  const float* b_ih1     = (const float*)d_in[13];
  const float* b_hh1     = (const float*)d_in[14];
  float* out = (float*)d_out;
  char* ws = (char*)d_ws;

  float* xp0            = (float*)(ws);                    // 4,718,592 B (gru phase)
  float2* part          = (float2*)(ws);                   // 3,932,160 B (fc phase, reuses xp0)
  unsigned* exch        = (unsigned*)(ws + 4718592);       //    65,536
  unsigned* flags       = (unsigned*)(ws + 4784128);       //       256 (padded)
  float* logz           = (float*)(ws + 4784384);          //     6,144
  unsigned short* abf   = (unsigned short*)(ws + 4790528); //   786,432
  unsigned short* wbf   = (unsigned short*)(ws + 5576960); // 20,512,768
  float* wT             = (float*)(ws + 26089728);         //   393,216 -> ~26.5 MB

  castw_kernel<<<dim3((NPADC*64 + 255)/256), dim3(256), 0, stream>>>(fc_w, wbf);
  wt_kernel<<<dim3((E*G3 + 255)/256), dim3(256), 0, stream>>>(w_ih0, wT, flags);
  xp0_kernel<<<dim3(96), dim3(256), 0, stream>>>(locations, times, embed, wT, w_ih0, b_ih0, xp0);

  GruArgs ga{xp0, traj, labels, w_hh0, b_hh0, w_ih1, w_hh1, b_ih1, b_hh1,
             exch, flags, abf};
  void* kargs[] = { &ga };
  hipLaunchCooperativeKernel((void*)gru_kernel, dim3(16), dim3(384), kargs, 0, stream);

  fc_kernel<0><<<dim3(12, 313), dim3(256), 0, stream>>>(abf, wbf, fc_b, nullptr, nullptr, part);
  stats_kernel<<<dim3(B*T), dim3(64), 0, stream>>>(part, logz);
  fc_kernel<1><<<dim3(12, 313), dim3(256), 0, stream>>>(abf, wbf, fc_b, logz, out, nullptr);
  tm_kernel<<<dim3(B*T), dim3(64), 0, stream>>>(out);
}